// Round 13
// baseline (585.807 us; speedup 1.0000x reference)
//
#include <hip/hip_runtime.h>
#include <math.h>

// LRU (Laguerre ladder) recurrence, MI355X.
// *** DIAGNOSTIC ROUND: r6 kernel with phase 2 executed TWICE (identical
// values rewritten; deterministic) so the kernel dispatch exceeds the
// harness's ~155us fillBuffer dispatches and lands in rocprof's top-5,
// exposing WRITE_SIZE / FETCH_SIZE / VALUBusy / Occupancy for our datapath.
// Perf numbers this round are sacrificial; divide work by 2 when reading. ***
//
// Base (r6, verified 81.6us): one (b,f) chain per 64-lane wave; lane l owns
// hidden index l; wavefront-skew over t. Ring 96 slots x 64 floats (24KB).
// Chunk q ds_read at k=16q+86, stored 16 STEPs later via ping-pong A/B.
#define TT 512
#define FF 64
#define BB 32
#define HH 64
#define NSLOT 96
#define RSF 64                       // floats per ring row

__device__ __forceinline__ float shift_up1(float v, int j16) {
    // lane l gets lane l-1's value across the whole wave
    int s1 = __builtin_amdgcn_update_dpp(0, __float_as_int(v), 0x111, 0xf, 0xf, true);  // row_shr:1
    int s2 = __builtin_amdgcn_update_dpp(0, __float_as_int(v), 0x142, 0xf, 0xf, false); // row_bcast:15
    return __int_as_float((j16 == 0) ? s2 : s1);
}

// one recurrence step; MASKED is a compile-time literal
#define STEP(MASKED, UK) do {                                          \
    const float shifted_ = shift_up1(vlast, j16);                      \
    const float nbr_cur_ = isj0 ? (UK) : shifted_;                     \
    float v_ = fmaf(cA, nbr_cur_, fmaf(a, prev, -nbr_prev));           \
    if (MASKED) {                                                      \
        const bool live_ = ((unsigned)t < (unsigned)TT);               \
        v_ = live_ ? v_ : prev;                                        \
        if (live_) *(float*)((char*)ring + vaddr) = v_;                \
    } else {                                                           \
        *(float*)((char*)ring + vaddr) = v_;                           \
    }                                                                  \
    vaddr += 256; vaddr = (vaddr == vtop) ? vbase : vaddr;             \
    nbr_prev = isj0 ? 0.f : nbr_cur_;                                  \
    prev = v_; vlast = v_;                                             \
    ++t;                                                               \
} while (0)

// read next chunk (16 rows) from ring into a float4 set + capture its out ptr.
// Register i holds row (l>>4) + 4*i of the chunk, cols 4*j16..4*j16+3.
#define READS(G0, G1, G2, G3, OPP) do {                                \
    const float* rp_ = ring + (sb + (l >> 4)) * RSF + (j16 << 2);      \
    G0 = *(const float4*)(rp_ + 0 * 4 * RSF);                          \
    G1 = *(const float4*)(rp_ + 1 * 4 * RSF);                          \
    G2 = *(const float4*)(rp_ + 2 * 4 * RSF);                          \
    G3 = *(const float4*)(rp_ + 3 * 4 * RSF);                          \
    OPP = ochunk + ((size_t)(l >> 4) << 12) + (j16 << 2);              \
    ochunk += 16 * 4096;                                               \
    sb += 16; if (sb == NSLOT) sb = 0;                                 \
} while (0)

// register i goes to t = chunk_base + (l>>4) + 4*i  (out t-stride = 4096 floats)
#define STORES(G0, G1, G2, G3, OPP) do {                               \
    *(float4*)(OPP + (size_t)0 * 16384) = G0;                          \
    *(float4*)(OPP + (size_t)1 * 16384) = G1;                          \
    *(float4*)(OPP + (size_t)2 * 16384) = G2;                          \
    *(float4*)(OPP + (size_t)3 * 16384) = G3;                          \
} while (0)

#define PT_RD_A do { READS(gA0,gA1,gA2,gA3, opA); } while (0)
#define PT_AB   do { STORES(gA0,gA1,gA2,gA3, opA); READS(gB0,gB1,gB2,gB3, opB); } while (0)
#define PT_BA   do { STORES(gB0,gB1,gB2,gB3, opB); READS(gA0,gA1,gA2,gA3, opA); } while (0)
#define NOPT    do {} while (0)

// one 32-STEP half; flush points after STEP i_=6 and i_=22 (k = 16q+86 pattern)
#define HALF(UREG, HS, MASKED, P6, P22) do {                           \
    _Pragma("unroll")                                                  \
    for (int i_ = 0; i_ < 32; ++i_) {                                  \
        const float uk_ = __int_as_float(                              \
            __builtin_amdgcn_readlane(__float_as_int(UREG), (HS) * 32 + i_)); \
        STEP(MASKED, uk_);                                             \
        if (i_ == 6)  { P6; }                                          \
        if (i_ == 22) { P22; }                                         \
    }                                                                  \
} while (0)

// steady pair: 4 flush points, uniform {store A, read B} / {store B, read A}
#define PAIR_STEADY(UREG) do {                                         \
    HALF(UREG, 0, false, PT_AB, PT_BA);                                \
    HALF(UREG, 1, false, PT_AB, PT_BA);                                \
} while (0)

__global__ __launch_bounds__(64) void lru_kernel(
    const float* __restrict__ x,      // (B,T,I)
    const float* __restrict__ W,      // (F,I)
    const float* __restrict__ relax,  // (F,)
    float* __restrict__ out)          // (B,T,F,H) ++ (F,B,H)
{
    __shared__ float ring[NSLOT * RSF];   // 24576 B -> 6 blocks/CU

    const int w = blockIdx.x;             // 2048 waves, one per (b,f) chain
    const int b = w >> 6;
    const int f = w & 63;
    const int l = threadIdx.x;            // hidden index owned by this lane
    const int j16 = l & 15;

    // ---------- phase 1: u[c*64+l] = dot(x[b,c*64+l,:], W[f,:]) into 8 VGPRs ----------
    float ua[8];
    {
        const float4* __restrict__ Wv = reinterpret_cast<const float4*>(W) + (size_t)f * 16;
        float4 wreg[16];
        #pragma unroll
        for (int q = 0; q < 16; ++q) wreg[q] = Wv[q];
        const float4* __restrict__ xb = reinterpret_cast<const float4*>(x) + (size_t)b * TT * 16;
        #pragma unroll
        for (int c = 0; c < 8; ++c) {
            const int tt = (c << 6) + l;
            const float4* xv = xb + (size_t)tt * 16;
            float acc = 0.f;
            #pragma unroll
            for (int q = 0; q < 16; ++q) {
                const float4 xq = xv[q], wq = wreg[q];
                acc = fmaf(xq.x, wq.x, fmaf(xq.y, wq.y, fmaf(xq.z, wq.z, fmaf(xq.w, wq.w, acc))));
            }
            ua[c] = acc;
        }
    }

    const float rel = relax[f];
    const float a  = sqrtf(rel);
    const float gn = sqrtf(1.0f - rel);
    const bool isj0 = (l == 0);
    const float cA = isj0 ? gn : a;
    const int vbase = l << 2;
    const int vtop  = NSLOT * 256 + vbase;

    float prevFinal = 0.f;

    // ---------- phase 2, executed twice (DIAGNOSTIC; identical values) ----------
    #pragma unroll 1
    for (int rep = 0; rep < 2; ++rep) {
        float prev = 0.f, nbr_prev = 0.f, vlast = 0.f;
        int t = -l;                            // lane's timestep; advances every STEP
        int vaddr = ((NSLOT - l) % NSLOT) * 256 + vbase;   // slot (t mod 96), col l
        int sb = 0;                            // ring slot base of next chunk to read
        float* ochunk = out + (size_t)b * (TT * FF * HH) + (size_t)f * HH;
        float4 gA0, gA1, gA2, gA3, gB0, gB1, gB2, gB3;
        float *opA = nullptr, *opB = nullptr;

        // pair 0 (k=0..63): masked ramp-in, ring fills, no flush
        HALF(ua[0], 0, true, NOPT, NOPT);
        HALF(ua[0], 1, true, NOPT, NOPT);

        // pair 1 (k=64..127): first read at k=86 (chunk 0), then steady pattern
        HALF(ua[1], 0, false, NOPT, PT_RD_A);
        HALF(ua[1], 1, false, PT_AB, PT_BA);

        // pairs 2..7 (k=128..511): steady state, 4 chunks per pair
        PAIR_STEADY(ua[2]);
        PAIR_STEADY(ua[3]);
        PAIR_STEADY(ua[4]);
        PAIR_STEADY(ua[5]);
        PAIR_STEADY(ua[6]);
        PAIR_STEADY(ua[7]);

        // pair 8 (k=512..575): masked ramp-out; flushes chunks 27..30
        HALF(ua[7], 0, true, PT_AB, PT_BA);
        HALF(ua[7], 1, true, PT_AB, PT_BA);

        // post-loop: store chunk 30 (in A), then read+store chunk 31
        STORES(gA0, gA1, gA2, gA3, opA);
        READS(gB0, gB1, gB2, gB3, opB);
        STORES(gB0, gB1, gB2, gB3, opB);

        prevFinal = prev;
    }

    // h_final = y[T-1][l]
    out[(size_t)BB * TT * FF * HH + ((size_t)f * BB + b) * HH + l] = prevFinal;
}

extern "C" void kernel_launch(void* const* d_in, const int* in_sizes, int n_in,
                              void* d_out, int out_size, void* d_ws, size_t ws_size,
                              hipStream_t stream) {
    const float* x     = (const float*)d_in[0];
    const float* W     = (const float*)d_in[1];
    const float* relax = (const float*)d_in[2];
    float* out = (float*)d_out;
    lru_kernel<<<dim3(2048), dim3(64), 0, stream>>>(x, W, relax, out);
}

// Round 14
// 569.078 us; speedup vs baseline: 1.0294x; 1.0294x over previous
//
#include <hip/hip_runtime.h>
#include <math.h>

// LRU (Laguerre ladder) recurrence, MI355X.
// *** DIAGNOSTIC ROUND: r6 kernel with phase 2 executed TWICE (identical
// values rewritten; deterministic) so the kernel dispatch exceeds the
// harness's ~155us fillBuffer dispatches and lands in rocprof's top-5,
// exposing WRITE_SIZE / FETCH_SIZE / VALUBusy / Occupancy for our datapath.
// Perf numbers this round are sacrificial; divide work by 2 when reading. ***
//
// Base (r6, verified 81.6us): one (b,f) chain per 64-lane wave; lane l owns
// hidden index l; wavefront-skew over t. Ring 96 slots x 64 floats (24KB).
// Chunk q ds_read at k=16q+86, stored 16 STEPs later via ping-pong A/B.
#define TT 512
#define FF 64
#define BB 32
#define HH 64
#define NSLOT 96
#define RSF 64                       // floats per ring row

__device__ __forceinline__ float shift_up1(float v, int j16) {
    // lane l gets lane l-1's value across the whole wave
    int s1 = __builtin_amdgcn_update_dpp(0, __float_as_int(v), 0x111, 0xf, 0xf, true);  // row_shr:1
    int s2 = __builtin_amdgcn_update_dpp(0, __float_as_int(v), 0x142, 0xf, 0xf, false); // row_bcast:15
    return __int_as_float((j16 == 0) ? s2 : s1);
}

// one recurrence step; MASKED is a compile-time literal
#define STEP(MASKED, UK) do {                                          \
    const float shifted_ = shift_up1(vlast, j16);                      \
    const float nbr_cur_ = isj0 ? (UK) : shifted_;                     \
    float v_ = fmaf(cA, nbr_cur_, fmaf(a, prev, -nbr_prev));           \
    if (MASKED) {                                                      \
        const bool live_ = ((unsigned)t < (unsigned)TT);               \
        v_ = live_ ? v_ : prev;                                        \
        if (live_) *(float*)((char*)ring + vaddr) = v_;                \
    } else {                                                           \
        *(float*)((char*)ring + vaddr) = v_;                           \
    }                                                                  \
    vaddr += 256; vaddr = (vaddr == vtop) ? vbase : vaddr;             \
    nbr_prev = isj0 ? 0.f : nbr_cur_;                                  \
    prev = v_; vlast = v_;                                             \
    ++t;                                                               \
} while (0)

// read next chunk (16 rows) from ring into a float4 set + capture its out ptr.
// Register i holds row (l>>4) + 4*i of the chunk, cols 4*j16..4*j16+3.
#define READS(G0, G1, G2, G3, OPP) do {                                \
    const float* rp_ = ring + (sb + (l >> 4)) * RSF + (j16 << 2);      \
    G0 = *(const float4*)(rp_ + 0 * 4 * RSF);                          \
    G1 = *(const float4*)(rp_ + 1 * 4 * RSF);                          \
    G2 = *(const float4*)(rp_ + 2 * 4 * RSF);                          \
    G3 = *(const float4*)(rp_ + 3 * 4 * RSF);                          \
    OPP = ochunk + ((size_t)(l >> 4) << 12) + (j16 << 2);              \
    ochunk += 16 * 4096;                                               \
    sb += 16; if (sb == NSLOT) sb = 0;                                 \
} while (0)

// register i goes to t = chunk_base + (l>>4) + 4*i  (out t-stride = 4096 floats)
#define STORES(G0, G1, G2, G3, OPP) do {                               \
    *(float4*)(OPP + (size_t)0 * 16384) = G0;                          \
    *(float4*)(OPP + (size_t)1 * 16384) = G1;                          \
    *(float4*)(OPP + (size_t)2 * 16384) = G2;                          \
    *(float4*)(OPP + (size_t)3 * 16384) = G3;                          \
} while (0)

#define PT_RD_A do { READS(gA0,gA1,gA2,gA3, opA); } while (0)
#define PT_AB   do { STORES(gA0,gA1,gA2,gA3, opA); READS(gB0,gB1,gB2,gB3, opB); } while (0)
#define PT_BA   do { STORES(gB0,gB1,gB2,gB3, opB); READS(gA0,gA1,gA2,gA3, opA); } while (0)
#define NOPT    do {} while (0)

// one 32-STEP half; flush points after STEP i_=6 and i_=22 (k = 16q+86 pattern)
#define HALF(UREG, HS, MASKED, P6, P22) do {                           \
    _Pragma("unroll")                                                  \
    for (int i_ = 0; i_ < 32; ++i_) {                                  \
        const float uk_ = __int_as_float(                              \
            __builtin_amdgcn_readlane(__float_as_int(UREG), (HS) * 32 + i_)); \
        STEP(MASKED, uk_);                                             \
        if (i_ == 6)  { P6; }                                          \
        if (i_ == 22) { P22; }                                         \
    }                                                                  \
} while (0)

// steady pair: 4 flush points, uniform {store A, read B} / {store B, read A}
#define PAIR_STEADY(UREG) do {                                         \
    HALF(UREG, 0, false, PT_AB, PT_BA);                                \
    HALF(UREG, 1, false, PT_AB, PT_BA);                                \
} while (0)

__global__ __launch_bounds__(64) void lru_kernel(
    const float* __restrict__ x,      // (B,T,I)
    const float* __restrict__ W,      // (F,I)
    const float* __restrict__ relax,  // (F,)
    float* __restrict__ out)          // (B,T,F,H) ++ (F,B,H)
{
    __shared__ float ring[NSLOT * RSF];   // 24576 B -> 6 blocks/CU

    const int w = blockIdx.x;             // 2048 waves, one per (b,f) chain
    const int b = w >> 6;
    const int f = w & 63;
    const int l = threadIdx.x;            // hidden index owned by this lane
    const int j16 = l & 15;

    // ---------- phase 1: u[c*64+l] = dot(x[b,c*64+l,:], W[f,:]) into 8 VGPRs ----------
    float ua[8];
    {
        const float4* __restrict__ Wv = reinterpret_cast<const float4*>(W) + (size_t)f * 16;
        float4 wreg[16];
        #pragma unroll
        for (int q = 0; q < 16; ++q) wreg[q] = Wv[q];
        const float4* __restrict__ xb = reinterpret_cast<const float4*>(x) + (size_t)b * TT * 16;
        #pragma unroll
        for (int c = 0; c < 8; ++c) {
            const int tt = (c << 6) + l;
            const float4* xv = xb + (size_t)tt * 16;
            float acc = 0.f;
            #pragma unroll
            for (int q = 0; q < 16; ++q) {
                const float4 xq = xv[q], wq = wreg[q];
                acc = fmaf(xq.x, wq.x, fmaf(xq.y, wq.y, fmaf(xq.z, wq.z, fmaf(xq.w, wq.w, acc))));
            }
            ua[c] = acc;
        }
    }

    const float rel = relax[f];
    const float a  = sqrtf(rel);
    const float gn = sqrtf(1.0f - rel);
    const bool isj0 = (l == 0);
    const float cA = isj0 ? gn : a;
    const int vbase = l << 2;
    const int vtop  = NSLOT * 256 + vbase;

    float prevFinal = 0.f;

    // ---------- phase 2, executed twice (DIAGNOSTIC; identical values) ----------
    #pragma unroll 1
    for (int rep = 0; rep < 2; ++rep) {
        float prev = 0.f, nbr_prev = 0.f, vlast = 0.f;
        int t = -l;                            // lane's timestep; advances every STEP
        int vaddr = ((NSLOT - l) % NSLOT) * 256 + vbase;   // slot (t mod 96), col l
        int sb = 0;                            // ring slot base of next chunk to read
        float* ochunk = out + (size_t)b * (TT * FF * HH) + (size_t)f * HH;
        float4 gA0, gA1, gA2, gA3, gB0, gB1, gB2, gB3;
        float *opA = nullptr, *opB = nullptr;

        // pair 0 (k=0..63): masked ramp-in, ring fills, no flush
        HALF(ua[0], 0, true, NOPT, NOPT);
        HALF(ua[0], 1, true, NOPT, NOPT);

        // pair 1 (k=64..127): first read at k=86 (chunk 0), then steady pattern
        HALF(ua[1], 0, false, NOPT, PT_RD_A);
        HALF(ua[1], 1, false, PT_AB, PT_BA);

        // pairs 2..7 (k=128..511): steady state, 4 chunks per pair
        PAIR_STEADY(ua[2]);
        PAIR_STEADY(ua[3]);
        PAIR_STEADY(ua[4]);
        PAIR_STEADY(ua[5]);
        PAIR_STEADY(ua[6]);
        PAIR_STEADY(ua[7]);

        // pair 8 (k=512..575): masked ramp-out; flushes chunks 27..30
        HALF(ua[7], 0, true, PT_AB, PT_BA);
        HALF(ua[7], 1, true, PT_AB, PT_BA);

        // post-loop: store chunk 30 (in A), then read+store chunk 31
        STORES(gA0, gA1, gA2, gA3, opA);
        READS(gB0, gB1, gB2, gB3, opB);
        STORES(gB0, gB1, gB2, gB3, opB);

        prevFinal = prev;
    }

    // h_final = y[T-1][l]
    out[(size_t)BB * TT * FF * HH + ((size_t)f * BB + b) * HH + l] = prevFinal;
}

extern "C" void kernel_launch(void* const* d_in, const int* in_sizes, int n_in,
                              void* d_out, int out_size, void* d_ws, size_t ws_size,
                              hipStream_t stream) {
    const float* x     = (const float*)d_in[0];
    const float* W     = (const float*)d_in[1];
    const float* relax = (const float*)d_in[2];
    float* out = (float*)d_out;
    lru_kernel<<<dim3(2048), dim3(64), 0, stream>>>(x, W, relax, out);
}

// Round 15
// 548.681 us; speedup vs baseline: 1.0677x; 1.0372x over previous
//
#include <hip/hip_runtime.h>
#include <math.h>

// LRU (Laguerre ladder) recurrence, MI355X.
// *** DIAGNOSTIC ROUND: r6 kernel with phase 2 executed TWICE (identical
// values rewritten; deterministic) so the kernel dispatch exceeds the
// harness's ~155us fillBuffer dispatches and lands in rocprof's top-5,
// exposing WRITE_SIZE / FETCH_SIZE / VALUBusy / Occupancy for our datapath.
// Perf numbers this round are sacrificial; divide work by 2 when reading. ***
//
// Base (r6, verified 81.6us): one (b,f) chain per 64-lane wave; lane l owns
// hidden index l; wavefront-skew over t. Ring 96 slots x 64 floats (24KB).
// Chunk q ds_read at k=16q+86, stored 16 STEPs later via ping-pong A/B.
#define TT 512
#define FF 64
#define BB 32
#define HH 64
#define NSLOT 96
#define RSF 64                       // floats per ring row

__device__ __forceinline__ float shift_up1(float v, int j16) {
    // lane l gets lane l-1's value across the whole wave
    int s1 = __builtin_amdgcn_update_dpp(0, __float_as_int(v), 0x111, 0xf, 0xf, true);  // row_shr:1
    int s2 = __builtin_amdgcn_update_dpp(0, __float_as_int(v), 0x142, 0xf, 0xf, false); // row_bcast:15
    return __int_as_float((j16 == 0) ? s2 : s1);
}

// one recurrence step; MASKED is a compile-time literal
#define STEP(MASKED, UK) do {                                          \
    const float shifted_ = shift_up1(vlast, j16);                      \
    const float nbr_cur_ = isj0 ? (UK) : shifted_;                     \
    float v_ = fmaf(cA, nbr_cur_, fmaf(a, prev, -nbr_prev));           \
    if (MASKED) {                                                      \
        const bool live_ = ((unsigned)t < (unsigned)TT);               \
        v_ = live_ ? v_ : prev;                                        \
        if (live_) *(float*)((char*)ring + vaddr) = v_;                \
    } else {                                                           \
        *(float*)((char*)ring + vaddr) = v_;                           \
    }                                                                  \
    vaddr += 256; vaddr = (vaddr == vtop) ? vbase : vaddr;             \
    nbr_prev = isj0 ? 0.f : nbr_cur_;                                  \
    prev = v_; vlast = v_;                                             \
    ++t;                                                               \
} while (0)

// read next chunk (16 rows) from ring into a float4 set + capture its out ptr.
// Register i holds row (l>>4) + 4*i of the chunk, cols 4*j16..4*j16+3.
#define READS(G0, G1, G2, G3, OPP) do {                                \
    const float* rp_ = ring + (sb + (l >> 4)) * RSF + (j16 << 2);      \
    G0 = *(const float4*)(rp_ + 0 * 4 * RSF);                          \
    G1 = *(const float4*)(rp_ + 1 * 4 * RSF);                          \
    G2 = *(const float4*)(rp_ + 2 * 4 * RSF);                          \
    G3 = *(const float4*)(rp_ + 3 * 4 * RSF);                          \
    OPP = ochunk + ((size_t)(l >> 4) << 12) + (j16 << 2);              \
    ochunk += 16 * 4096;                                               \
    sb += 16; if (sb == NSLOT) sb = 0;                                 \
} while (0)

// register i goes to t = chunk_base + (l>>4) + 4*i  (out t-stride = 4096 floats)
#define STORES(G0, G1, G2, G3, OPP) do {                               \
    *(float4*)(OPP + (size_t)0 * 16384) = G0;                          \
    *(float4*)(OPP + (size_t)1 * 16384) = G1;                          \
    *(float4*)(OPP + (size_t)2 * 16384) = G2;                          \
    *(float4*)(OPP + (size_t)3 * 16384) = G3;                          \
} while (0)

#define PT_RD_A do { READS(gA0,gA1,gA2,gA3, opA); } while (0)
#define PT_AB   do { STORES(gA0,gA1,gA2,gA3, opA); READS(gB0,gB1,gB2,gB3, opB); } while (0)
#define PT_BA   do { STORES(gB0,gB1,gB2,gB3, opB); READS(gA0,gA1,gA2,gA3, opA); } while (0)
#define NOPT    do {} while (0)

// one 32-STEP half; flush points after STEP i_=6 and i_=22 (k = 16q+86 pattern)
#define HALF(UREG, HS, MASKED, P6, P22) do {                           \
    _Pragma("unroll")                                                  \
    for (int i_ = 0; i_ < 32; ++i_) {                                  \
        const float uk_ = __int_as_float(                              \
            __builtin_amdgcn_readlane(__float_as_int(UREG), (HS) * 32 + i_)); \
        STEP(MASKED, uk_);                                             \
        if (i_ == 6)  { P6; }                                          \
        if (i_ == 22) { P22; }                                         \
    }                                                                  \
} while (0)

// steady pair: 4 flush points, uniform {store A, read B} / {store B, read A}
#define PAIR_STEADY(UREG) do {                                         \
    HALF(UREG, 0, false, PT_AB, PT_BA);                                \
    HALF(UREG, 1, false, PT_AB, PT_BA);                                \
} while (0)

__global__ __launch_bounds__(64) void lru_kernel(
    const float* __restrict__ x,      // (B,T,I)
    const float* __restrict__ W,      // (F,I)
    const float* __restrict__ relax,  // (F,)
    float* __restrict__ out)          // (B,T,F,H) ++ (F,B,H)
{
    __shared__ float ring[NSLOT * RSF];   // 24576 B -> 6 blocks/CU

    const int w = blockIdx.x;             // 2048 waves, one per (b,f) chain
    const int b = w >> 6;
    const int f = w & 63;
    const int l = threadIdx.x;            // hidden index owned by this lane
    const int j16 = l & 15;

    // ---------- phase 1: u[c*64+l] = dot(x[b,c*64+l,:], W[f,:]) into 8 VGPRs ----------
    float ua[8];
    {
        const float4* __restrict__ Wv = reinterpret_cast<const float4*>(W) + (size_t)f * 16;
        float4 wreg[16];
        #pragma unroll
        for (int q = 0; q < 16; ++q) wreg[q] = Wv[q];
        const float4* __restrict__ xb = reinterpret_cast<const float4*>(x) + (size_t)b * TT * 16;
        #pragma unroll
        for (int c = 0; c < 8; ++c) {
            const int tt = (c << 6) + l;
            const float4* xv = xb + (size_t)tt * 16;
            float acc = 0.f;
            #pragma unroll
            for (int q = 0; q < 16; ++q) {
                const float4 xq = xv[q], wq = wreg[q];
                acc = fmaf(xq.x, wq.x, fmaf(xq.y, wq.y, fmaf(xq.z, wq.z, fmaf(xq.w, wq.w, acc))));
            }
            ua[c] = acc;
        }
    }

    const float rel = relax[f];
    const float a  = sqrtf(rel);
    const float gn = sqrtf(1.0f - rel);
    const bool isj0 = (l == 0);
    const float cA = isj0 ? gn : a;
    const int vbase = l << 2;
    const int vtop  = NSLOT * 256 + vbase;

    float prevFinal = 0.f;

    // ---------- phase 2, executed twice (DIAGNOSTIC; identical values) ----------
    #pragma unroll 1
    for (int rep = 0; rep < 2; ++rep) {
        float prev = 0.f, nbr_prev = 0.f, vlast = 0.f;
        int t = -l;                            // lane's timestep; advances every STEP
        int vaddr = ((NSLOT - l) % NSLOT) * 256 + vbase;   // slot (t mod 96), col l
        int sb = 0;                            // ring slot base of next chunk to read
        float* ochunk = out + (size_t)b * (TT * FF * HH) + (size_t)f * HH;
        float4 gA0, gA1, gA2, gA3, gB0, gB1, gB2, gB3;
        float *opA = nullptr, *opB = nullptr;

        // pair 0 (k=0..63): masked ramp-in, ring fills, no flush
        HALF(ua[0], 0, true, NOPT, NOPT);
        HALF(ua[0], 1, true, NOPT, NOPT);

        // pair 1 (k=64..127): first read at k=86 (chunk 0), then steady pattern
        HALF(ua[1], 0, false, NOPT, PT_RD_A);
        HALF(ua[1], 1, false, PT_AB, PT_BA);

        // pairs 2..7 (k=128..511): steady state, 4 chunks per pair
        PAIR_STEADY(ua[2]);
        PAIR_STEADY(ua[3]);
        PAIR_STEADY(ua[4]);
        PAIR_STEADY(ua[5]);
        PAIR_STEADY(ua[6]);
        PAIR_STEADY(ua[7]);

        // pair 8 (k=512..575): masked ramp-out; flushes chunks 27..30
        HALF(ua[7], 0, true, PT_AB, PT_BA);
        HALF(ua[7], 1, true, PT_AB, PT_BA);

        // post-loop: store chunk 30 (in A), then read+store chunk 31
        STORES(gA0, gA1, gA2, gA3, opA);
        READS(gB0, gB1, gB2, gB3, opB);
        STORES(gB0, gB1, gB2, gB3, opB);

        prevFinal = prev;
    }

    // h_final = y[T-1][l]
    out[(size_t)BB * TT * FF * HH + ((size_t)f * BB + b) * HH + l] = prevFinal;
}

extern "C" void kernel_launch(void* const* d_in, const int* in_sizes, int n_in,
                              void* d_out, int out_size, void* d_ws, size_t ws_size,
                              hipStream_t stream) {
    const float* x     = (const float*)d_in[0];
    const float* W     = (const float*)d_in[1];
    const float* relax = (const float*)d_in[2];
    float* out = (float*)d_out;
    lru_kernel<<<dim3(2048), dim3(64), 0, stream>>>(x, W, relax, out);
}

// Round 16
// 82.455 us; speedup vs baseline: 7.1046x; 6.6543x over previous
//
#include <hip/hip_runtime.h>
#include <math.h>

// LRU (Laguerre ladder) recurrence, MI355X.
// B=32, T=512, I=64, F=64, H=64. Output: (B,T,F,H) f32 ++ h_final (F,B,H) f32.
// One (b,f) chain per 64-lane wave; lane l owns hidden index l; wavefront-skew
// over t (lane l computes row t = k - l at global step k).
// Ring: 96 slots x 64 floats = 24 KB LDS -> 6 blocks/CU.
// Flush: 16-row chunks; chunk q is ds_read at k = 16q+86 (margin 8 after lane-63
// completes row 16q+15 at k=16q+78; margin 10 before slot reuse at k=16q+96).
//
// r16 change vs r6 (verified 81.6us): FOUR rotating register sets A,B,C,D
// instead of ping-pong A/B. Read@p -> store@p+1 (16 STEPs, unchanged), but a
// set's registers are rewritten 3 points (48 STEPs ~ 600 cyc) after its store
// issues, moving the store-data-consumption WAR wait off the critical path.
// r15 counters justified this: VALUBusy 8.6%, bank-conflicts 0, hbm 18% peak,
// dur >> traffic/BW -> latency(vmcnt)-bound, not BW/issue/conflict-bound.
#define TT 512
#define FF 64
#define BB 32
#define HH 64
#define NSLOT 96
#define RSF 64                       // floats per ring row

__device__ __forceinline__ float shift_up1(float v, int j16) {
    // lane l gets lane l-1's value across the whole wave
    int s1 = __builtin_amdgcn_update_dpp(0, __float_as_int(v), 0x111, 0xf, 0xf, true);  // row_shr:1
    int s2 = __builtin_amdgcn_update_dpp(0, __float_as_int(v), 0x142, 0xf, 0xf, false); // row_bcast:15
    return __int_as_float((j16 == 0) ? s2 : s1);
}

// one recurrence step; MASKED is a compile-time literal
#define STEP(MASKED, UK) do {                                          \
    const float shifted_ = shift_up1(vlast, j16);                      \
    const float nbr_cur_ = isj0 ? (UK) : shifted_;                     \
    float v_ = fmaf(cA, nbr_cur_, fmaf(a, prev, -nbr_prev));           \
    if (MASKED) {                                                      \
        const bool live_ = ((unsigned)t < (unsigned)TT);               \
        v_ = live_ ? v_ : prev;                                        \
        if (live_) *(float*)((char*)ring + vaddr) = v_;                \
    } else {                                                           \
        *(float*)((char*)ring + vaddr) = v_;                           \
    }                                                                  \
    vaddr += 256; vaddr = (vaddr == vtop) ? vbase : vaddr;             \
    nbr_prev = isj0 ? 0.f : nbr_cur_;                                  \
    prev = v_; vlast = v_;                                             \
    ++t;                                                               \
} while (0)

// read next chunk (16 rows) from ring into a float4 set + capture its out ptr.
// Register i holds row (l>>4) + 4*i of the chunk, cols 4*j16..4*j16+3.
#define READS(G0, G1, G2, G3, OPP) do {                                \
    const float* rp_ = ring + (sb + (l >> 4)) * RSF + (j16 << 2);      \
    G0 = *(const float4*)(rp_ + 0 * 4 * RSF);                          \
    G1 = *(const float4*)(rp_ + 1 * 4 * RSF);                          \
    G2 = *(const float4*)(rp_ + 2 * 4 * RSF);                          \
    G3 = *(const float4*)(rp_ + 3 * 4 * RSF);                          \
    OPP = ochunk + ((size_t)(l >> 4) << 12) + (j16 << 2);              \
    ochunk += 16 * 4096;                                               \
    sb += 16; if (sb == NSLOT) sb = 0;                                 \
} while (0)

// register i goes to t = chunk_base + (l>>4) + 4*i  (out t-stride = 4096 floats)
#define STORES(G0, G1, G2, G3, OPP) do {                               \
    *(float4*)(OPP + (size_t)0 * 16384) = G0;                          \
    *(float4*)(OPP + (size_t)1 * 16384) = G1;                          \
    *(float4*)(OPP + (size_t)2 * 16384) = G2;                          \
    *(float4*)(OPP + (size_t)3 * 16384) = G3;                          \
} while (0)

// 4-set rotation: store the set read one point ago, read the next set.
#define PT_RD_A do { READS(gA0,gA1,gA2,gA3, opA); } while (0)
#define PT_AB   do { STORES(gA0,gA1,gA2,gA3, opA); READS(gB0,gB1,gB2,gB3, opB); } while (0)
#define PT_BC   do { STORES(gB0,gB1,gB2,gB3, opB); READS(gC0,gC1,gC2,gC3, opC); } while (0)
#define PT_CD   do { STORES(gC0,gC1,gC2,gC3, opC); READS(gD0,gD1,gD2,gD3, opD); } while (0)
#define PT_DA   do { STORES(gD0,gD1,gD2,gD3, opD); READS(gA0,gA1,gA2,gA3, opA); } while (0)
#define NOPT    do {} while (0)

// one 32-STEP half; flush points after STEP i_=6 and i_=22 (k = 16q+86 pattern)
#define HALF(UREG, HS, MASKED, P6, P22) do {                           \
    _Pragma("unroll")                                                  \
    for (int i_ = 0; i_ < 32; ++i_) {                                  \
        const float uk_ = __int_as_float(                              \
            __builtin_amdgcn_readlane(__float_as_int(UREG), (HS) * 32 + i_)); \
        STEP(MASKED, uk_);                                             \
        if (i_ == 6)  { P6; }                                          \
        if (i_ == 22) { P22; }                                         \
    }                                                                  \
} while (0)

// steady pair (points p ≡ 0..3 mod 4): CD, DA, AB, BC
#define PAIR_STEADY(UREG) do {                                         \
    HALF(UREG, 0, false, PT_CD, PT_DA);                                \
    HALF(UREG, 1, false, PT_AB, PT_BC);                                \
} while (0)

__global__ __launch_bounds__(64) void lru_kernel(
    const float* __restrict__ x,      // (B,T,I)
    const float* __restrict__ W,      // (F,I)
    const float* __restrict__ relax,  // (F,)
    float* __restrict__ out)          // (B,T,F,H) ++ (F,B,H)
{
    __shared__ float ring[NSLOT * RSF];   // 24576 B -> 6 blocks/CU

    const int w = blockIdx.x;             // 2048 waves, one per (b,f) chain
    const int b = w >> 6;
    const int f = w & 63;
    const int l = threadIdx.x;            // hidden index owned by this lane
    const int j16 = l & 15;

    // ---------- phase 1: u[c*64+l] = dot(x[b,c*64+l,:], W[f,:]) into 8 VGPRs ----------
    float ua[8];
    {
        const float4* __restrict__ Wv = reinterpret_cast<const float4*>(W) + (size_t)f * 16;
        float4 wreg[16];
        #pragma unroll
        for (int q = 0; q < 16; ++q) wreg[q] = Wv[q];
        const float4* __restrict__ xb = reinterpret_cast<const float4*>(x) + (size_t)b * TT * 16;
        #pragma unroll
        for (int c = 0; c < 8; ++c) {
            const int tt = (c << 6) + l;
            const float4* xv = xb + (size_t)tt * 16;
            float acc = 0.f;
            #pragma unroll
            for (int q = 0; q < 16; ++q) {
                const float4 xq = xv[q], wq = wreg[q];
                acc = fmaf(xq.x, wq.x, fmaf(xq.y, wq.y, fmaf(xq.z, wq.z, fmaf(xq.w, wq.w, acc))));
            }
            ua[c] = acc;
        }
    }

    // ---------- phase 2: skewed recurrence ----------
    const float rel = relax[f];
    const float a  = sqrtf(rel);
    const float gn = sqrtf(1.0f - rel);
    const bool isj0 = (l == 0);
    const float cA = isj0 ? gn : a;

    float prev = 0.f, nbr_prev = 0.f, vlast = 0.f;
    int t = -l;                            // lane's timestep; advances every STEP

    const int vbase = l << 2;
    const int vtop  = NSLOT * 256 + vbase;
    int vaddr = ((NSLOT - l) % NSLOT) * 256 + vbase;   // slot (t mod 96), col l

    int sb = 0;                            // ring slot base of next chunk to read
    float* ochunk = out + (size_t)b * (TT * FF * HH) + (size_t)f * HH;
    float4 gA0, gA1, gA2, gA3, gB0, gB1, gB2, gB3;
    float4 gC0, gC1, gC2, gC3, gD0, gD1, gD2, gD3;
    float *opA = nullptr, *opB = nullptr, *opC = nullptr, *opD = nullptr;

    // pair 0 (k=0..63): masked ramp-in, ring fills, no flush
    HALF(ua[0], 0, true, NOPT, NOPT);
    HALF(ua[0], 1, true, NOPT, NOPT);

    // pair 1 (k=64..127): p1@k=86 read c0->A; p2: store A, read c1->B;
    // p3: store B, read c2->C
    HALF(ua[1], 0, false, NOPT, PT_RD_A);
    HALF(ua[1], 1, false, PT_AB, PT_BC);

    // pairs 2..7 (k=128..511): steady state, points (CD, DA, AB, BC) per pair
    PAIR_STEADY(ua[2]);
    PAIR_STEADY(ua[3]);
    PAIR_STEADY(ua[4]);
    PAIR_STEADY(ua[5]);
    PAIR_STEADY(ua[6]);
    PAIR_STEADY(ua[7]);

    // pair 8 (k=512..575): masked ramp-out; same point pattern (p28..p31)
    HALF(ua[7], 0, true, PT_CD, PT_DA);
    HALF(ua[7], 1, true, PT_AB, PT_BC);

    // post-loop: store c30 (in C), then read+store c31 (via D; all writes done)
    STORES(gC0, gC1, gC2, gC3, opC);
    READS(gD0, gD1, gD2, gD3, opD);
    STORES(gD0, gD1, gD2, gD3, opD);

    // h_final = y[T-1][l] (frozen in prev)
    out[(size_t)BB * TT * FF * HH + ((size_t)f * BB + b) * HH + l] = prev;
}

extern "C" void kernel_launch(void* const* d_in, const int* in_sizes, int n_in,
                              void* d_out, int out_size, void* d_ws, size_t ws_size,
                              hipStream_t stream) {
    const float* x     = (const float*)d_in[0];
    const float* W     = (const float*)d_in[1];
    const float* relax = (const float*)d_in[2];
    float* out = (float*)d_out;
    lru_kernel<<<dim3(2048), dim3(64), 0, stream>>>(x, W, relax, out);
}